// Round 3
// baseline (543.076 us; speedup 1.0000x reference)
//
#include <hip/hip_runtime.h>

// ---------------------------------------------------------------------------
// InternalSequenceEmbedder: bidirectional diagonal linear SSM + MLP.
// B=32, T=8192, E=256, D=32, H=32, M=64.
//
// Round 5 (= round 4 resubmit after infra failure):
//  k0_prep : fold Wpi@Win -> WuT bf16 [64n][256k]; sigmoid/log2 decay; bf16
//            B-layout epilogue weights; combined bias bc.
//  kA      : per (b,chunk=256 tok), 512 threads / 8 waves. 4 sub-tiles of
//            64 tokens staged to LDS (coalesced float4 -> bf16), MFMA
//            proj with WuT B-fragments HOISTED to registers (loaded once
//            per block, not per sub-tile). 8 barrier drains per block
//            (was 16). Scan: round-2 4x64 chains on 256 of 512 threads.
//            LDS 67.6KB -> 2 blocks/CU, 16 waves/CU, 2 clean rounds.
//  k3_carry: cross-chunk carry scan; all 32 Ebuf values prefetched to
//            registers before the serial fma chain.
//  kB      : all-MFMA epilogue, phase1+phase2 fused per 16-token tile
//            (wave-private Yt/Zw, no barrier). LDS 24KB + launch_bounds
//            (256,4) -> 4 blocks/CU: full 1024-block grid resident.
// ---------------------------------------------------------------------------

typedef unsigned short u16;
typedef unsigned int   u32;
typedef __bf16 bf16x8 __attribute__((ext_vector_type(8)));
typedef float  f32x4  __attribute__((ext_vector_type(4)));

constexpr int BB = 32, TT = 8192, NCH = 64;
constexpr int BT = BB * TT;            // 262144 tokens
constexpr int LCH = 256;               // scan chunk length
constexpr int NCHUNK = TT / LCH;       // 32

#define MFMA16(av, bv, cc) __builtin_amdgcn_mfma_f32_16x16x32_bf16((av), (bv), (cc), 0, 0, 0)

__device__ __forceinline__ u16 f2bf(float x) {
    union { float f; u32 u; } v; v.f = x;
    u32 r = (v.u + 0x7FFFu + ((v.u >> 16) & 1u)) >> 16;
    return (u16)r;
}
__device__ __forceinline__ float bf2f(u16 x) {
    union { u32 u; float f; } v; v.u = ((u32)x) << 16;
    return v.f;
}
__device__ __forceinline__ float gelu_tanh(float x) {
    // jax.nn.gelu default (approximate=True)
    float inner = 0.7978845608028654f * fmaf(0.044715f * x, x * x, x);
    float ez = __expf(2.f * inner);
    float t = 1.f - 2.f / (ez + 1.f);        // NaN-free tanh
    return 0.5f * x * (1.f + t);
}

// ---------------------------------------------------------------------------
__global__ void k0_prep(const float* __restrict__ Wpi, const float* __restrict__ bpi,
                        const float* __restrict__ fWin, const float* __restrict__ fbin,
                        const float* __restrict__ floga,
                        const float* __restrict__ bWin, const float* __restrict__ bbin,
                        const float* __restrict__ bloga,
                        const float* __restrict__ fW1, const float* __restrict__ bW1,
                        const float* __restrict__ fW2, const float* __restrict__ bW2,
                        const float* __restrict__ fb2, const float* __restrict__ bb2,
                        const float* __restrict__ fWout, const float* __restrict__ bWout,
                        const float* __restrict__ Wpo, const float* __restrict__ bpo,
                        u16* __restrict__ WuT, float* __restrict__ bu,
                        float* __restrict__ a_arr, float* __restrict__ l2a,
                        u16* __restrict__ W1Tbf, u16* __restrict__ W2poCatT,
                        u16* __restrict__ WoutTbf, u16* __restrict__ WpoCatT,
                        float* __restrict__ bc)
{
    const int blk = blockIdx.x, tid = threadIdx.x;
    if (blk < 64) {                       // WuT row n = (Wpi @ Win) column n
        const float* Win = (blk < 32) ? fWin : bWin;
        const int nn = blk & 31;
        float s = 0.f;
        #pragma unroll
        for (int d = 0; d < 32; ++d) s = fmaf(Wpi[tid * 32 + d], Win[d * 32 + nn], s);
        WuT[blk * 256 + tid] = f2bf(s);
        if (tid == 0) {
            const float* bin = (blk < 32) ? fbin : bbin;
            float sb = bin[nn];
            for (int d = 0; d < 32; ++d) sb = fmaf(bpi[d], Win[d * 32 + nn], sb);
            bu[blk] = sb;
        }
    } else if (blk == 64) {
        if (tid < 64) {                   // decay + log2
            const float* lg = (tid < 32) ? floga : bloga;
            float a = 1.f / (1.f + __expf(-lg[tid & 31]));
            a_arr[tid] = a;
            l2a[tid] = log2f(a);
        } else if (tid < 96) {            // bc = bpo + fb2@WpoF + bb2@WpoB
            int i = tid - 64;
            float s = bpo[i];
            for (int d = 0; d < 32; ++d) s = fmaf(fb2[d], Wpo[d * 32 + i], s);
            for (int d = 0; d < 32; ++d) s = fmaf(bb2[d], Wpo[(32 + d) * 32 + i], s);
            bc[i] = s;
        }
    } else if (blk == 65 || blk == 66) {  // W1T bf16 [dir][64n][32k]
        int dir = blk - 65;
        const float* W1 = dir ? bW1 : fW1;
        for (int x = tid; x < 2048; x += 256) {
            int n = x >> 5, k = x & 31;
            W1Tbf[dir * 2048 + n * 32 + k] = f2bf(W1[k * 64 + n]);
        }
    } else if (blk == 67 || blk == 68) {  // W2@Wpo fold -> [32n][128k], k=dir*64+j
        int dir = blk - 67;
        const float* W2 = dir ? bW2 : fW2;
        const float* Wp = Wpo + dir * 32 * 32;
        for (int x = tid; x < 2048; x += 256) {
            int j = x >> 5, i = x & 31;
            float s = 0.f;
            for (int d = 0; d < 32; ++d) s = fmaf(W2[j * 32 + d], Wp[d * 32 + i], s);
            W2poCatT[i * 128 + dir * 64 + j] = f2bf(s);
        }
    } else if (blk == 69 || blk == 70) {  // WoutT bf16 [dir][32n][32k]
        int dir = blk - 69;
        const float* Wout = dir ? bWout : fWout;
        for (int x = tid; x < 1024; x += 256) {
            int n = x >> 5, k = x & 31;
            WoutTbf[dir * 1024 + n * 32 + k] = f2bf(Wout[k * 32 + n]);
        }
    } else {                              // WpoCatT bf16 [32n][64k]
        for (int x = tid; x < 2048; x += 256) {
            int n = x >> 6, k = x & 63;
            WpoCatT[n * 64 + k] = f2bf(Wpo[k * 32 + n]);
        }
    }
}

// ---------------------------------------------------------------------------
// kA: fused projection + chunk-local scan. Block = (b, chunk) = 256 tokens,
// 512 threads / 8 waves. 4 sub-tiles of 64 tokens staged to LDS; wave
// (wr,wc) owns a 16x32 quadrant of each sub-tile's 64x64 output. WuT
// B-fragments are sub-tile-invariant -> hoisted to registers once per block.
// Scan: 4x64 chains (round-2 numerics) on threads 0..255.
// LDS: As 64x264 u16 (33.8KB) + utile 256x64 u16 (32KB) + eSub 1KB.
__global__ __launch_bounds__(512, 4) void kA_proj_scan(const float* __restrict__ e,
    const u16* __restrict__ WuT, const float* __restrict__ bu,
    const float* __restrict__ a_arr, const float* __restrict__ l2a,
    u16* __restrict__ h, float* __restrict__ Ebuf)
{
    __shared__ __align__(16) u16 As[64][264];
    __shared__ __align__(16) u16 utile[256 * 64];
    __shared__ float eSub[64][4];
    const int tid = threadIdx.x;
    const int blk = blockIdx.x;
    const size_t t0 = (size_t)blk * 256;
    const int lane = tid & 63, wave = tid >> 6;
    const int row16 = lane & 15, quad = lane >> 4;
    const int wr = (wave & 3) * 16;          // sub-tile row offset for this wave
    const int wc = (wave >> 2) * 32;         // col offset

    // hoist B-fragments (sub-tile invariant): 16 x bf16x8 = 64 VGPR
    bf16x8 bvv[8][2];
    #pragma unroll
    for (int ks = 0; ks < 8; ++ks)
        #pragma unroll
        for (int c2 = 0; c2 < 2; ++c2)
            bvv[ks][c2] = *reinterpret_cast<const bf16x8*>(WuT + (wc + c2 * 16 + row16) * 256 + ks * 32 + quad * 8);

    #pragma unroll 1
    for (int s = 0; s < 4; ++s) {            // 4 sub-tiles of 64 tokens
        const float4* eg = reinterpret_cast<const float4*>(e + (t0 + s * 64) * 256);
        #pragma unroll
        for (int it = 0; it < 8; ++it) {
            int i = tid + it * 512;          // 4096 float4 = 64 rows x 64 f4
            int r = i >> 6, kk = (i & 63) << 2;
            float4 v = eg[i];
            uint2 pk;
            pk.x = (u32)f2bf(v.x) | ((u32)f2bf(v.y) << 16);
            pk.y = (u32)f2bf(v.z) | ((u32)f2bf(v.w) << 16);
            *reinterpret_cast<uint2*>(&As[r][kk]) = pk;
        }
        __syncthreads();
        f32x4 acc[2] = {{0.f,0.f,0.f,0.f},{0.f,0.f,0.f,0.f}};
        #pragma unroll
        for (int ks = 0; ks < 8; ++ks) {
            bf16x8 av = *reinterpret_cast<const bf16x8*>(&As[wr + row16][ks * 32 + quad * 8]);
            #pragma unroll
            for (int c2 = 0; c2 < 2; ++c2)
                acc[c2] = MFMA16(av, bvv[ks][c2], acc[c2]);
        }
        #pragma unroll
        for (int c2 = 0; c2 < 2; ++c2) {     // C/D: col=lane&15, row=quad*4+r
            int col = wc + c2 * 16 + row16;
            float bias = bu[col];
            #pragma unroll
            for (int r = 0; r < 4; ++r) {
                int trow = s * 64 + wr + quad * 4 + r;
                utile[trow * 64 + col] = f2bf(acc[c2][r] + bias);
            }
        }
        __syncthreads();
    }

    // ---- chunk-local scan on utile (64 ch x 4 sub-chunks of 64) ----
    const int ch = tid & 63, sid = (tid >> 6) & 3;
    const float a = a_arr[ch];
    const bool fwd = (ch < 32);
    if (tid < 256) {
        float hh = 0.f;
        if (fwd) {
            for (int i = 0; i < 64; ++i) { int t = sid * 64 + i;
                hh = fmaf(a, hh, bf2f(utile[t * 64 + ch])); utile[t * 64 + ch] = f2bf(hh); }
        } else {
            for (int i = 63; i >= 0; --i) { int t = sid * 64 + i;
                hh = fmaf(a, hh, bf2f(utile[t * 64 + ch])); utile[t * 64 + ch] = f2bf(hh); }
        }
        eSub[ch][sid] = hh;
    }
    __syncthreads();
    if (tid < 256) {
        const float A = exp2f(64.f * l2a[ch]);           // a^64
        float cin = 0.f;
        if (fwd) { for (int j = 0; j < sid; ++j) cin = fmaf(A, cin, eSub[ch][j]); }
        else     { for (int j = 3; j > sid; --j) cin = fmaf(A, cin, eSub[ch][j]); }
        if (fwd && sid == 3)  Ebuf[(size_t)blk * 64 + ch] = fmaf(A, cin, eSub[ch][3]);
        if (!fwd && sid == 0) Ebuf[(size_t)blk * 64 + ch] = fmaf(A, cin, eSub[ch][0]);
        float p = cin;
        if (fwd) {
            for (int i = 0; i < 64; ++i) { int t = sid * 64 + i; p *= a;
                utile[t * 64 + ch] = f2bf(bf2f(utile[t * 64 + ch]) + p); }
        } else {
            for (int i = 63; i >= 0; --i) { int t = sid * 64 + i; p *= a;
                utile[t * 64 + ch] = f2bf(bf2f(utile[t * 64 + ch]) + p); }
        }
    }
    __syncthreads();
    uint4* gw = reinterpret_cast<uint4*>(h + t0 * 64);
    const uint4* s4 = reinterpret_cast<const uint4*>(utile);
    #pragma unroll
    for (int i = 0; i < 4; ++i) gw[tid + 512 * i] = s4[tid + 512 * i];
}

// ---------------------------------------------------------------------------
// k3: cross-chunk carry scan. All 32 Ebuf values prefetched to registers
// (independent loads) before the serial chain -> one HBM latency, not 32.
__global__ void k3_carry(const float* __restrict__ Ebuf, float* __restrict__ Cin,
                         const float* __restrict__ l2a)
{
    int tid = blockIdx.x * 256 + threadIdx.x;
    if (tid >= BB * NCH) return;
    int b = tid >> 6, ch = tid & 63;
    float aL = exp2f((float)LCH * l2a[ch]);      // a^256
    const size_t base = (size_t)b * NCHUNK * 64 + ch;
    float ev[NCHUNK];
    #pragma unroll
    for (int c = 0; c < NCHUNK; ++c) ev[c] = Ebuf[base + (size_t)c * 64];
    float S = 0.f;
    if (ch < 32) {
        #pragma unroll
        for (int c = 0; c < NCHUNK; ++c) {
            Cin[base + (size_t)c * 64] = S; S = fmaf(aL, S, ev[c]);
        }
    } else {
        #pragma unroll
        for (int c = NCHUNK - 1; c >= 0; --c) {
            Cin[base + (size_t)c * 64] = S; S = fmaf(aL, S, ev[c]);
        }
    }
}

// ---------------------------------------------------------------------------
// kB: all-MFMA epilogue, phase1+phase2 fused per 16-token tile. Block =
// (b, chunk) = 256 tokens; wave owns 64 rows = 4 tiles. Yt/Zw are wave-
// private -> NO barrier anywhere. XOR swizzle kills the 16-way column-read
// conflicts. LDS 24KB + launch_bounds(256,4) -> whole grid resident.
__global__ __launch_bounds__(256, 4) void kB_out(const u16* __restrict__ h,
    const float* __restrict__ Cin, const float* __restrict__ l2a,
    const u16* __restrict__ WoutTbf, const float* __restrict__ fbout, const float* __restrict__ bbout,
    const u16* __restrict__ W1Tbf, const float* __restrict__ fb1, const float* __restrict__ bb1,
    const u16* __restrict__ WpoCatT, const u16* __restrict__ W2poCatT,
    const float* __restrict__ bc, float* __restrict__ out)
{
    __shared__ __align__(16) u16 Yt[4][16 * 64];     // per-wave Y tile, swizzled
    __shared__ __align__(16) u16 Zw[4][16 * 128];    // per-wave Z scratch, swizzled
    const int tid = threadIdx.x;
    const int blk = blockIdx.x;
    const size_t t0 = (size_t)blk * 256;
    const int lane = tid & 63, wave = tid >> 6;
    const int row16 = lane & 15, quad = lane >> 4;
    const float* cinp = Cin + (size_t)blk * 64;      // uniform per block
    u16* myY = Yt[wave];
    u16* myZ = Zw[wave];

    #pragma unroll 1
    for (int rr = 0; rr < 4; ++rr) {
        const int rt = wave * 4 + rr;
        const int kpos = rt * 16 + row16;            // token pos in chunk

        // ---- phase 1: Y = (h + cin*a^off) @ Wout + bout -> myY (16x64) ----
        #pragma unroll
        for (int dir = 0; dir < 2; ++dir) {
            uint4 hv = *reinterpret_cast<const uint4*>(h + (t0 + kpos) * 64 + dir * 32 + quad * 8);
            u32 hw[4] = {hv.x, hv.y, hv.z, hv.w};
            const float off = dir ? (float)(LCH - kpos) : (float)(kpos + 1);
            union { bf16x8 v; u16 s[8]; } af;
            #pragma unroll
            for (int j = 0; j < 8; ++j) {
                int chn = dir * 32 + quad * 8 + j;
                float f = bf2f((u16)((hw[j >> 1] >> ((j & 1) * 16)) & 0xFFFFu));
                f = fmaf(cinp[chn], exp2f(off * l2a[chn]), f);
                af.s[j] = f2bf(f);
            }
            f32x4 yv[2] = {{0.f,0.f,0.f,0.f},{0.f,0.f,0.f,0.f}};
            #pragma unroll
            for (int nt = 0; nt < 2; ++nt) {
                bf16x8 bv = *reinterpret_cast<const bf16x8*>(WoutTbf + dir * 1024 + (nt * 16 + row16) * 32 + quad * 8);
                yv[nt] = MFMA16(af.v, bv, yv[nt]);
            }
            const float* boutp = dir ? bbout : fbout;
            #pragma unroll
            for (int nt = 0; nt < 2; ++nt) {
                float bb = boutp[nt * 16 + row16];
                #pragma unroll
                for (int r = 0; r < 4; ++r) {
                    int row = quad * 4 + r;                  // tile-local row
                    int col = dir * 32 + nt * 16 + row16;
                    int cs = (col >> 3) ^ (row & 7);
                    myY[row * 64 + cs * 8 + (col & 7)] = f2bf(yv[nt][r] + bb);
                }
            }
        }

        // ---- phase 2: OUT = Ycat@Wpo + gelu(Y@W1+b1)@W2po + bc ----
        f32x4 o0 = {0.f,0.f,0.f,0.f}, o1 = {0.f,0.f,0.f,0.f};

        // residual path: Ycat (K=64) @ WpoCat
        #pragma unroll
        for (int kb = 0; kb < 2; ++kb) {
            int cs = (kb * 4 + quad) ^ (row16 & 7);
            bf16x8 av = *reinterpret_cast<const bf16x8*>(&myY[row16 * 64 + cs * 8]);
            bf16x8 bv0 = *reinterpret_cast<const bf16x8*>(WpoCatT + (row16) * 64 + kb * 32 + quad * 8);
            bf16x8 bv1 = *reinterpret_cast<const bf16x8*>(WpoCatT + (16 + row16) * 64 + kb * 32 + quad * 8);
            o0 = MFMA16(av, bv0, o0);
            o1 = MFMA16(av, bv1, o1);
        }
        // Z = gelu(Y_dir @ W1_dir + b1) -> myZ (16x128, swizzled)
        #pragma unroll
        for (int dir = 0; dir < 2; ++dir) {
            int cs = (dir * 4 + quad) ^ (row16 & 7);
            bf16x8 av = *reinterpret_cast<const bf16x8*>(&myY[row16 * 64 + cs * 8]);
            const float* b1p = dir ? bb1 : fb1;
            #pragma unroll
            for (int nt2 = 0; nt2 < 4; ++nt2) {
                f32x4 z = {0.f,0.f,0.f,0.f};
                bf16x8 bv = *reinterpret_cast<const bf16x8*>(W1Tbf + dir * 2048 + (nt2 * 16 + row16) * 32 + quad * 8);
                z = MFMA16(av, bv, z);
                float bb = b1p[nt2 * 16 + row16];
                #pragma unroll
                for (int r = 0; r < 4; ++r) {
                    float zz = gelu_tanh(z[r] + bb);
                    int zrow = quad * 4 + r;
                    int zcol = dir * 64 + nt2 * 16 + row16;
                    int zcs = (zcol >> 3) ^ (zrow & 7);
                    myZ[zrow * 128 + zcs * 8 + (zcol & 7)] = f2bf(zz);
                }
            }
        }
        // MLP path: Zcat (K=128) @ W2poCat
        #pragma unroll
        for (int kb = 0; kb < 4; ++kb) {
            int zcs = (kb * 4 + quad) ^ (row16 & 7);
            bf16x8 av = *reinterpret_cast<const bf16x8*>(&myZ[row16 * 128 + zcs * 8]);
            bf16x8 bv0 = *reinterpret_cast<const bf16x8*>(W2poCatT + (row16) * 128 + kb * 32 + quad * 8);
            bf16x8 bv1 = *reinterpret_cast<const bf16x8*>(W2poCatT + (16 + row16) * 128 + kb * 32 + quad * 8);
            o0 = MFMA16(av, bv0, o0);
            o1 = MFMA16(av, bv1, o1);
        }
        #pragma unroll
        for (int r = 0; r < 4; ++r) {
            size_t row = t0 + rt * 16 + quad * 4 + r;
            out[row * 32 + row16]      = o0[r] + bc[row16];
            out[row * 32 + 16 + row16] = o1[r] + bc[16 + row16];
        }
    }
}

// ---------------------------------------------------------------------------
extern "C" void kernel_launch(void* const* d_in, const int* in_sizes, int n_in,
                              void* d_out, int out_size, void* d_ws, size_t ws_size,
                              hipStream_t stream)
{
    (void)in_sizes; (void)n_in; (void)out_size; (void)ws_size;
    const float* e     = (const float*)d_in[0];
    const float* Wpi   = (const float*)d_in[1];
    const float* bpi   = (const float*)d_in[2];
    const float* Wpo   = (const float*)d_in[3];
    const float* bpo   = (const float*)d_in[4];
    const float* fWin  = (const float*)d_in[5];
    const float* fbin  = (const float*)d_in[6];
    const float* floga = (const float*)d_in[7];
    const float* fWout = (const float*)d_in[8];
    const float* fbout = (const float*)d_in[9];
    const float* fW1   = (const float*)d_in[10];
    const float* fb1   = (const float*)d_in[11];
    const float* fW2   = (const float*)d_in[12];
    const float* fb2   = (const float*)d_in[13];
    const float* bWin  = (const float*)d_in[14];
    const float* bbin  = (const float*)d_in[15];
    const float* bloga = (const float*)d_in[16];
    const float* bWout = (const float*)d_in[17];
    const float* bbout = (const float*)d_in[18];
    const float* bW1   = (const float*)d_in[19];
    const float* bb1   = (const float*)d_in[20];
    const float* bW2   = (const float*)d_in[21];
    const float* bb2   = (const float*)d_in[22];
    float* outp = (float*)d_out;

    char* ws = (char*)d_ws;
    size_t off = 0;
    auto walloc = [&](size_t bytes) { void* p = ws + off; off += (bytes + 255) & ~(size_t)255; return p; };
    u16*   hbuf  = (u16*)  walloc((size_t)BT * 64 * 2);       // 32 MB h_local
    u16*   WuT   = (u16*)  walloc(64 * 256 * 2);
    float* bu    = (float*)walloc(64 * 4);
    float* a_arr = (float*)walloc(64 * 4);
    float* l2a   = (float*)walloc(64 * 4);
    float* Ebuf  = (float*)walloc((size_t)BB * NCHUNK * 64 * 4);
    float* Cin   = (float*)walloc((size_t)BB * NCHUNK * 64 * 4);
    u16*   W1Tbf    = (u16*)walloc(2 * 64 * 32 * 2);
    u16*   W2poCatT = (u16*)walloc(32 * 128 * 2);
    u16*   WoutTbf  = (u16*)walloc(2 * 32 * 32 * 2);
    u16*   WpoCatT  = (u16*)walloc(32 * 64 * 2);
    float* bc    = (float*)walloc(32 * 4);

    k0_prep<<<72, 256, 0, stream>>>(Wpi, bpi, fWin, fbin, floga, bWin, bbin, bloga,
                                    fW1, bW1, fW2, bW2, fb2, bb2, fWout, bWout, Wpo, bpo,
                                    WuT, bu, a_arr, l2a, W1Tbf, W2poCatT, WoutTbf, WpoCatT, bc);
    kA_proj_scan<<<BB * NCHUNK, 512, 0, stream>>>(e, WuT, bu, a_arr, l2a, hbuf, Ebuf);
    k3_carry<<<8, 256, 0, stream>>>(Ebuf, Cin, l2a);
    kB_out<<<BB * NCHUNK, 256, 0, stream>>>(hbuf, Cin, l2a,
                                            WoutTbf, fbout, bbout,
                                            W1Tbf, fb1, bb1,
                                            WpoCatT, W2poCatT, bc, outp);
}

// Round 4
// 466.248 us; speedup vs baseline: 1.1648x; 1.1648x over previous
//
#include <hip/hip_runtime.h>

// ---------------------------------------------------------------------------
// InternalSequenceEmbedder: bidirectional diagonal linear SSM + MLP.
// B=32, T=8192, E=256, D=32, H=32, M=64.
//
// Round 6 = re-anchor: byte-exact 467.6us baseline (round-2 structure),
// single delta: k3_carry register-prefetch (identical numerics).
//  k0_prep : fold Wpi@Win -> WuT bf16 [64n][256k]; sigmoid/log2 decay; bf16
//            B-layout epilogue weights: WoutT[2][32n][32k], W1T[2][64n][32k],
//            WpoCatT[32n][64k], W2poCatT[32n][128k] (=W2@Wpo fold);
//            combined bias bc = bpo + fb2@WpoF + bb2@WpoB.
//  kA      : per (b,chunk=256 tok): MFMA proj e@Wu -> u in LDS (8 sub-tiles
//            of 32 tok), then in-LDS chunked scan (4x64 chains), write
//            h_local (bf16, coalesced) + per-chunk end states Ebuf.
//  k3_carry: cross-chunk carry scan (2048 series x 32 chunks); Ebuf
//            prefetched to registers before the serial fma chain.
//  kB      : all-MFMA epilogue (unfused two-phase, wave-private rows ->
//            no barrier). Y -> Yt LDS (XOR-swizzled); OUT = Ycat@Wpo +
//            gelu(Y@W1+b1)@(W2@Wpo) + bc; Z via per-wave swizzled LDS.
// ---------------------------------------------------------------------------

typedef unsigned short u16;
typedef unsigned int   u32;
typedef __bf16 bf16x8 __attribute__((ext_vector_type(8)));
typedef float  f32x4  __attribute__((ext_vector_type(4)));

constexpr int BB = 32, TT = 8192, NCH = 64;
constexpr int BT = BB * TT;            // 262144 tokens
constexpr int LCH = 256;               // scan chunk length
constexpr int NCHUNK = TT / LCH;       // 32

#define MFMA16(av, bv, cc) __builtin_amdgcn_mfma_f32_16x16x32_bf16((av), (bv), (cc), 0, 0, 0)

__device__ __forceinline__ u16 f2bf(float x) {
    union { float f; u32 u; } v; v.f = x;
    u32 r = (v.u + 0x7FFFu + ((v.u >> 16) & 1u)) >> 16;
    return (u16)r;
}
__device__ __forceinline__ float bf2f(u16 x) {
    union { u32 u; float f; } v; v.u = ((u32)x) << 16;
    return v.f;
}
__device__ __forceinline__ float gelu_tanh(float x) {
    // jax.nn.gelu default (approximate=True)
    float inner = 0.7978845608028654f * fmaf(0.044715f * x, x * x, x);
    float ez = __expf(2.f * inner);
    float t = 1.f - 2.f / (ez + 1.f);        // NaN-free tanh
    return 0.5f * x * (1.f + t);
}

// ---------------------------------------------------------------------------
__global__ void k0_prep(const float* __restrict__ Wpi, const float* __restrict__ bpi,
                        const float* __restrict__ fWin, const float* __restrict__ fbin,
                        const float* __restrict__ floga,
                        const float* __restrict__ bWin, const float* __restrict__ bbin,
                        const float* __restrict__ bloga,
                        const float* __restrict__ fW1, const float* __restrict__ bW1,
                        const float* __restrict__ fW2, const float* __restrict__ bW2,
                        const float* __restrict__ fb2, const float* __restrict__ bb2,
                        const float* __restrict__ fWout, const float* __restrict__ bWout,
                        const float* __restrict__ Wpo, const float* __restrict__ bpo,
                        u16* __restrict__ WuT, float* __restrict__ bu,
                        float* __restrict__ a_arr, float* __restrict__ l2a,
                        u16* __restrict__ W1Tbf, u16* __restrict__ W2poCatT,
                        u16* __restrict__ WoutTbf, u16* __restrict__ WpoCatT,
                        float* __restrict__ bc)
{
    const int blk = blockIdx.x, tid = threadIdx.x;
    if (blk < 64) {                       // WuT row n = (Wpi @ Win) column n
        const float* Win = (blk < 32) ? fWin : bWin;
        const int nn = blk & 31;
        float s = 0.f;
        #pragma unroll
        for (int d = 0; d < 32; ++d) s = fmaf(Wpi[tid * 32 + d], Win[d * 32 + nn], s);
        WuT[blk * 256 + tid] = f2bf(s);
        if (tid == 0) {
            const float* bin = (blk < 32) ? fbin : bbin;
            float sb = bin[nn];
            for (int d = 0; d < 32; ++d) sb = fmaf(bpi[d], Win[d * 32 + nn], sb);
            bu[blk] = sb;
        }
    } else if (blk == 64) {
        if (tid < 64) {                   // decay + log2
            const float* lg = (tid < 32) ? floga : bloga;
            float a = 1.f / (1.f + __expf(-lg[tid & 31]));
            a_arr[tid] = a;
            l2a[tid] = log2f(a);
        } else if (tid < 96) {            // bc = bpo + fb2@WpoF + bb2@WpoB
            int i = tid - 64;
            float s = bpo[i];
            for (int d = 0; d < 32; ++d) s = fmaf(fb2[d], Wpo[d * 32 + i], s);
            for (int d = 0; d < 32; ++d) s = fmaf(bb2[d], Wpo[(32 + d) * 32 + i], s);
            bc[i] = s;
        }
    } else if (blk == 65 || blk == 66) {  // W1T bf16 [dir][64n][32k]
        int dir = blk - 65;
        const float* W1 = dir ? bW1 : fW1;
        for (int x = tid; x < 2048; x += 256) {
            int n = x >> 5, k = x & 31;
            W1Tbf[dir * 2048 + n * 32 + k] = f2bf(W1[k * 64 + n]);
        }
    } else if (blk == 67 || blk == 68) {  // W2@Wpo fold -> [32n][128k], k=dir*64+j
        int dir = blk - 67;
        const float* W2 = dir ? bW2 : fW2;
        const float* Wp = Wpo + dir * 32 * 32;
        for (int x = tid; x < 2048; x += 256) {
            int j = x >> 5, i = x & 31;
            float s = 0.f;
            for (int d = 0; d < 32; ++d) s = fmaf(W2[j * 32 + d], Wp[d * 32 + i], s);
            W2poCatT[i * 128 + dir * 64 + j] = f2bf(s);
        }
    } else if (blk == 69 || blk == 70) {  // WoutT bf16 [dir][32n][32k]
        int dir = blk - 69;
        const float* Wout = dir ? bWout : fWout;
        for (int x = tid; x < 1024; x += 256) {
            int n = x >> 5, k = x & 31;
            WoutTbf[dir * 1024 + n * 32 + k] = f2bf(Wout[k * 32 + n]);
        }
    } else {                              // WpoCatT bf16 [32n][64k]
        for (int x = tid; x < 2048; x += 256) {
            int n = x >> 6, k = x & 63;
            WpoCatT[n * 64 + k] = f2bf(Wpo[k * 32 + n]);
        }
    }
}

// ---------------------------------------------------------------------------
// kA: fused projection + chunk-local scan. Block = (b, chunk) = 256 tokens.
// LDS: As 32x264 u16 (staging) + utile 256x64 u16 (u/h tile) + eSub. ~50 KB.
__global__ __launch_bounds__(256) void kA_proj_scan(const float* __restrict__ e,
    const u16* __restrict__ WuT, const float* __restrict__ bu,
    const float* __restrict__ a_arr, const float* __restrict__ l2a,
    u16* __restrict__ h, float* __restrict__ Ebuf)
{
    __shared__ __align__(16) u16 As[32][264];
    __shared__ __align__(16) u16 utile[256 * 64];
    __shared__ float eSub[64][4];
    const int tid = threadIdx.x;
    const int blk = blockIdx.x;
    const size_t t0 = (size_t)blk * 256;
    const int lane = tid & 63, wave = tid >> 6;
    const int row16 = lane & 15, quad = lane >> 4;
    const int wr = (wave & 1) * 16;          // sub-tile row offset for this wave
    const int wc = (wave >> 1) * 32;         // col offset

    #pragma unroll 1
    for (int s = 0; s < 8; ++s) {            // 8 sub-tiles of 32 tokens
        const float4* eg = reinterpret_cast<const float4*>(e + (t0 + s * 32) * 256);
        #pragma unroll
        for (int it = 0; it < 8; ++it) {
            int i = tid + it * 256;          // 2048 float4 = 32 rows x 256 k
            int r = i >> 6, kk = (i & 63) << 2;
            float4 v = eg[i];
            uint2 pk;
            pk.x = (u32)f2bf(v.x) | ((u32)f2bf(v.y) << 16);
            pk.y = (u32)f2bf(v.z) | ((u32)f2bf(v.w) << 16);
            *reinterpret_cast<uint2*>(&As[r][kk]) = pk;
        }
        __syncthreads();
        f32x4 acc[2] = {{0.f,0.f,0.f,0.f},{0.f,0.f,0.f,0.f}};
        #pragma unroll
        for (int ks = 0; ks < 8; ++ks) {
            bf16x8 av = *reinterpret_cast<const bf16x8*>(&As[wr + row16][ks * 32 + quad * 8]);
            #pragma unroll
            for (int c2 = 0; c2 < 2; ++c2) {
                bf16x8 bv = *reinterpret_cast<const bf16x8*>(WuT + (wc + c2 * 16 + row16) * 256 + ks * 32 + quad * 8);
                acc[c2] = MFMA16(av, bv, acc[c2]);
            }
        }
        #pragma unroll
        for (int c2 = 0; c2 < 2; ++c2) {     // C/D: col=lane&15, row=quad*4+r
            int col = wc + c2 * 16 + row16;
            float bias = bu[col];
            #pragma unroll
            for (int r = 0; r < 4; ++r) {
                int trow = s * 32 + wr + quad * 4 + r;
                utile[trow * 64 + col] = f2bf(acc[c2][r] + bias);
            }
        }
        __syncthreads();
    }

    // ---- chunk-local scan on utile (64 ch x 4 sub-chunks of 64) ----
    const int ch = tid & 63, sid = tid >> 6;
    const float a = a_arr[ch];
    const bool fwd = (ch < 32);
    float hh = 0.f;
    if (fwd) {
        for (int i = 0; i < 64; ++i) { int t = sid * 64 + i;
            hh = fmaf(a, hh, bf2f(utile[t * 64 + ch])); utile[t * 64 + ch] = f2bf(hh); }
    } else {
        for (int i = 63; i >= 0; --i) { int t = sid * 64 + i;
            hh = fmaf(a, hh, bf2f(utile[t * 64 + ch])); utile[t * 64 + ch] = f2bf(hh); }
    }
    eSub[ch][sid] = hh;
    __syncthreads();
    const float A = exp2f(64.f * l2a[ch]);               // a^64
    float cin = 0.f;
    if (fwd) { for (int j = 0; j < sid; ++j) cin = fmaf(A, cin, eSub[ch][j]); }
    else     { for (int j = 3; j > sid; --j) cin = fmaf(A, cin, eSub[ch][j]); }
    if (fwd && sid == 3)  Ebuf[(size_t)blk * 64 + ch] = fmaf(A, cin, eSub[ch][3]);
    if (!fwd && sid == 0) Ebuf[(size_t)blk * 64 + ch] = fmaf(A, cin, eSub[ch][0]);
    float p = cin;
    if (fwd) {
        for (int i = 0; i < 64; ++i) { int t = sid * 64 + i; p *= a;
            utile[t * 64 + ch] = f2bf(bf2f(utile[t * 64 + ch]) + p); }
    } else {
        for (int i = 63; i >= 0; --i) { int t = sid * 64 + i; p *= a;
            utile[t * 64 + ch] = f2bf(bf2f(utile[t * 64 + ch]) + p); }
    }
    __syncthreads();
    uint4* gw = reinterpret_cast<uint4*>(h + t0 * 64);
    const uint4* s4 = reinterpret_cast<const uint4*>(utile);
    #pragma unroll
    for (int i = 0; i < 8; ++i) gw[tid + 256 * i] = s4[tid + 256 * i];
}

// ---------------------------------------------------------------------------
// k3: cross-chunk carry scan. All 32 Ebuf values prefetched to registers
// (independent loads) before the serial chain -> one HBM latency, not 32.
// Identical fma order/numerics to the serial baseline version.
__global__ void k3_carry(const float* __restrict__ Ebuf, float* __restrict__ Cin,
                         const float* __restrict__ l2a)
{
    int tid = blockIdx.x * 256 + threadIdx.x;
    if (tid >= BB * NCH) return;
    int b = tid >> 6, ch = tid & 63;
    float aL = exp2f((float)LCH * l2a[ch]);      // a^256
    const size_t base = (size_t)b * NCHUNK * 64 + ch;
    float ev[NCHUNK];
    #pragma unroll
    for (int c = 0; c < NCHUNK; ++c) ev[c] = Ebuf[base + (size_t)c * 64];
    float S = 0.f;
    if (ch < 32) {
        #pragma unroll
        for (int c = 0; c < NCHUNK; ++c) {
            Cin[base + (size_t)c * 64] = S; S = fmaf(aL, S, ev[c]);
        }
    } else {
        #pragma unroll
        for (int c = NCHUNK - 1; c >= 0; --c) {
            Cin[base + (size_t)c * 64] = S; S = fmaf(aL, S, ev[c]);
        }
    }
}

// ---------------------------------------------------------------------------
// kB: all-MFMA epilogue. Block = (b, chunk) = 256 tokens; wave owns 64 rows.
// No __syncthreads needed: every LDS region is produced & consumed by the
// same wave. XOR swizzle (colblock ^ row&7) kills the 16-way column-read
// conflicts on the 128B-stride tiles.
__global__ __launch_bounds__(256) void kB_out(const u16* __restrict__ h,
    const float* __restrict__ Cin, const float* __restrict__ l2a,
    const u16* __restrict__ WoutTbf, const float* __restrict__ fbout, const float* __restrict__ bbout,
    const u16* __restrict__ W1Tbf, const float* __restrict__ fb1, const float* __restrict__ bb1,
    const u16* __restrict__ WpoCatT, const u16* __restrict__ W2poCatT,
    const float* __restrict__ bc, float* __restrict__ out)
{
    __shared__ __align__(16) u16 Yt[256 * 64];       // [token][dir*32+n], swizzled
    __shared__ __align__(16) u16 Zw[4][16 * 128];    // per-wave scratch, swizzled
    const int tid = threadIdx.x;
    const int blk = blockIdx.x;
    const size_t t0 = (size_t)blk * 256;
    const int lane = tid & 63, wave = tid >> 6;
    const int row16 = lane & 15, quad = lane >> 4;
    const float* cinp = Cin + (size_t)blk * 64;      // uniform per block

    // ---- phase 1: Y = (h + cin*a^off) @ Wout + bout  -> Yt ----
    #pragma unroll 1
    for (int rr = 0; rr < 4; ++rr) {
        const int rt = wave * 4 + rr;
        const int kpos = rt * 16 + row16;            // token pos in chunk (A row m)
        #pragma unroll
        for (int dir = 0; dir < 2; ++dir) {
            uint4 hv = *reinterpret_cast<const uint4*>(h + (t0 + kpos) * 64 + dir * 32 + quad * 8);
            u32 hw[4] = {hv.x, hv.y, hv.z, hv.w};
            const float off = dir ? (float)(LCH - kpos) : (float)(kpos + 1);
            union { bf16x8 v; u16 s[8]; } af;
            #pragma unroll
            for (int j = 0; j < 8; ++j) {
                int chn = dir * 32 + quad * 8 + j;
                float f = bf2f((u16)((hw[j >> 1] >> ((j & 1) * 16)) & 0xFFFFu));
                f = fmaf(cinp[chn], exp2f(off * l2a[chn]), f);
                af.s[j] = f2bf(f);
            }
            f32x4 yv[2] = {{0.f,0.f,0.f,0.f},{0.f,0.f,0.f,0.f}};
            #pragma unroll
            for (int nt = 0; nt < 2; ++nt) {
                bf16x8 bv = *reinterpret_cast<const bf16x8*>(WoutTbf + dir * 1024 + (nt * 16 + row16) * 32 + quad * 8);
                yv[nt] = MFMA16(af.v, bv, yv[nt]);
            }
            const float* boutp = dir ? bbout : fbout;
            #pragma unroll
            for (int nt = 0; nt < 2; ++nt) {
                float bb = boutp[nt * 16 + row16];
                #pragma unroll
                for (int r = 0; r < 4; ++r) {
                    int row = rt * 16 + quad * 4 + r;
                    int col = dir * 32 + nt * 16 + row16;
                    int cs = (col >> 3) ^ (row & 7);
                    Yt[row * 64 + cs * 8 + (col & 7)] = f2bf(yv[nt][r] + bb);
                }
            }
        }
    }

    // ---- phase 2: OUT = Ycat@Wpo + gelu(Y@W1+b1)@W2po + bc ----
    #pragma unroll 1
    for (int rr = 0; rr < 4; ++rr) {
        const int rt = wave * 4 + rr;
        const int arow = rt * 16 + row16;            // A row (token)
        f32x4 o0 = {0.f,0.f,0.f,0.f}, o1 = {0.f,0.f,0.f,0.f};

        // residual path: Ycat (K=64) @ WpoCat
        #pragma unroll
        for (int kb = 0; kb < 2; ++kb) {
            int cs = (kb * 4 + quad) ^ (arow & 7);
            bf16x8 av = *reinterpret_cast<const bf16x8*>(&Yt[arow * 64 + cs * 8]);
            bf16x8 bv0 = *reinterpret_cast<const bf16x8*>(WpoCatT + (row16) * 64 + kb * 32 + quad * 8);
            bf16x8 bv1 = *reinterpret_cast<const bf16x8*>(WpoCatT + (16 + row16) * 64 + kb * 32 + quad * 8);
            o0 = MFMA16(av, bv0, o0);
            o1 = MFMA16(av, bv1, o1);
        }
        // Z = gelu(Y_dir @ W1_dir + b1) -> Zw (per-wave, swizzled)
        #pragma unroll
        for (int dir = 0; dir < 2; ++dir) {
            int cs = (dir * 4 + quad) ^ (arow & 7);
            bf16x8 av = *reinterpret_cast<const bf16x8*>(&Yt[arow * 64 + cs * 8]);
            const float* b1p = dir ? bb1 : fb1;
            #pragma unroll
            for (int nt2 = 0; nt2 < 4; ++nt2) {
                f32x4 z = {0.f,0.f,0.f,0.f};
                bf16x8 bv = *reinterpret_cast<const bf16x8*>(W1Tbf + dir * 2048 + (nt2 * 16 + row16) * 32 + quad * 8);
                z = MFMA16(av, bv, z);
                float bb = b1p[nt2 * 16 + row16];
                #pragma unroll
                for (int r = 0; r < 4; ++r) {
                    float zz = gelu_tanh(z[r] + bb);
                    int zrow = quad * 4 + r;
                    int zcol = dir * 64 + nt2 * 16 + row16;
                    int zcs = (zcol >> 3) ^ (zrow & 7);
                    Zw[wave][zrow * 128 + zcs * 8 + (zcol & 7)] = f2bf(zz);
                }
            }
        }
        // MLP path: Zcat (K=128) @ W2poCat
        #pragma unroll
        for (int kb = 0; kb < 4; ++kb) {
            int zcs = (kb * 4 + quad) ^ (row16 & 7);
            bf16x8 av = *reinterpret_cast<const bf16x8*>(&Zw[wave][row16 * 128 + zcs * 8]);
            bf16x8 bv0 = *reinterpret_cast<const bf16x8*>(W2poCatT + (row16) * 128 + kb * 32 + quad * 8);
            bf16x8 bv1 = *reinterpret_cast<const bf16x8*>(W2poCatT + (16 + row16) * 128 + kb * 32 + quad * 8);
            o0 = MFMA16(av, bv0, o0);
            o1 = MFMA16(av, bv1, o1);
        }
        #pragma unroll
        for (int r = 0; r < 4; ++r) {
            size_t row = t0 + rt * 16 + quad * 4 + r;
            out[row * 32 + row16]      = o0[r] + bc[row16];
            out[row * 32 + 16 + row16] = o1[r] + bc[16 + row16];
        }
    }
}

// ---------------------------------------------------------------------------
extern "C" void kernel_launch(void* const* d_in, const int* in_sizes, int n_in,
                              void* d_out, int out_size, void* d_ws, size_t ws_size,
                              hipStream_t stream)
{
    (void)in_sizes; (void)n_in; (void)out_size; (void)ws_size;
    const float* e     = (const float*)d_in[0];
    const float* Wpi   = (const float*)d_in[1];
    const float* bpi   = (const float*)d_in[2];
    const float* Wpo   = (const float*)d_in[3];
    const float* bpo   = (const float*)d_in[4];
    const float* fWin  = (const float*)d_in[5];
    const float* fbin  = (const float*)d_in[6];
    const float* floga = (const float*)d_in[7];
    const float* fWout = (const float*)d_in[8];
    const float* fbout = (const float*)d_in[9];
    const float* fW1   = (const float*)d_in[10];
    const float* fb1   = (const float*)d_in[11];
    const float* fW2   = (const float*)d_in[12];
    const float* fb2   = (const float*)d_in[13];
    const float* bWin  = (const float*)d_in[14];
    const float* bbin  = (const float*)d_in[15];
    const float* bloga = (const float*)d_in[16];
    const float* bWout = (const float*)d_in[17];
    const float* bbout = (const float*)d_in[18];
    const float* bW1   = (const float*)d_in[19];
    const float* bb1   = (const float*)d_in[20];
    const float* bW2   = (const float*)d_in[21];
    const float* bb2   = (const float*)d_in[22];
    float* outp = (float*)d_out;

    char* ws = (char*)d_ws;
    size_t off = 0;
    auto walloc = [&](size_t bytes) { void* p = ws + off; off += (bytes + 255) & ~(size_t)255; return p; };
    u16*   hbuf  = (u16*)  walloc((size_t)BT * 64 * 2);       // 32 MB h_local
    u16*   WuT   = (u16*)  walloc(64 * 256 * 2);
    float* bu    = (float*)walloc(64 * 4);
    float* a_arr = (float*)walloc(64 * 4);
    float* l2a   = (float*)walloc(64 * 4);
    float* Ebuf  = (float*)walloc((size_t)BB * NCHUNK * 64 * 4);
    float* Cin   = (float*)walloc((size_t)BB * NCHUNK * 64 * 4);
    u16*   W1Tbf    = (u16*)walloc(2 * 64 * 32 * 2);
    u16*   W2poCatT = (u16*)walloc(32 * 128 * 2);
    u16*   WoutTbf  = (u16*)walloc(2 * 32 * 32 * 2);
    u16*   WpoCatT  = (u16*)walloc(32 * 64 * 2);
    float* bc    = (float*)walloc(32 * 4);

    k0_prep<<<72, 256, 0, stream>>>(Wpi, bpi, fWin, fbin, floga, bWin, bbin, bloga,
                                    fW1, bW1, fW2, bW2, fb2, bb2, fWout, bWout, Wpo, bpo,
                                    WuT, bu, a_arr, l2a, W1Tbf, W2poCatT, WoutTbf, WpoCatT, bc);
    kA_proj_scan<<<BB * NCHUNK, 256, 0, stream>>>(e, WuT, bu, a_arr, l2a, hbuf, Ebuf);
    k3_carry<<<8, 256, 0, stream>>>(Ebuf, Cin, l2a);
    kB_out<<<BB * NCHUNK, 256, 0, stream>>>(hbuf, Cin, l2a,
                                            WoutTbf, fbout, bbout,
                                            W1Tbf, fb1, bb1,
                                            WpoCatT, W2poCatT, bc, outp);
}

// Round 5
// 462.717 us; speedup vs baseline: 1.1737x; 1.0076x over previous
//
#include <hip/hip_runtime.h>

// ---------------------------------------------------------------------------
// InternalSequenceEmbedder: bidirectional diagonal linear SSM + MLP.
// B=32, T=8192, E=256, D=32, H=32, M=64.
//
// Round 7 = R6 anchor (466.2us) + ONE delta: native bf16 conversions.
// f2bf was a 4-op integer RNE; gfx950 has v_cvt_pk_bf16_f32 (RNE) and the
// scalar (__bf16) cast compiles to it. Bit-identical rounding, ~750 fewer
// VALU ops/thread in kA and kB each.
//  k0_prep : fold Wpi@Win -> WuT bf16 [64n][256k]; sigmoid/log2 decay; bf16
//            B-layout epilogue weights; combined bias bc.
//  kA      : per (b,chunk=256 tok): MFMA proj e@Wu -> u in LDS (8 sub-tiles
//            of 32 tok), then in-LDS chunked scan (4x64 chains), write
//            h_local (bf16, coalesced) + per-chunk end states Ebuf.
//  k3_carry: cross-chunk carry scan; Ebuf prefetched to registers.
//  kB      : all-MFMA epilogue (unfused two-phase, wave-private rows ->
//            no barrier). Y -> Yt LDS (XOR-swizzled); OUT = Ycat@Wpo +
//            gelu(Y@W1+b1)@(W2@Wpo) + bc; Z via per-wave swizzled LDS.
// ---------------------------------------------------------------------------

typedef unsigned short u16;
typedef unsigned int   u32;
typedef __bf16 bf16x2 __attribute__((ext_vector_type(2)));
typedef __bf16 bf16x8 __attribute__((ext_vector_type(8)));
typedef float  f32x4  __attribute__((ext_vector_type(4)));

constexpr int BB = 32, TT = 8192, NCH = 64;
constexpr int BT = BB * TT;            // 262144 tokens
constexpr int LCH = 256;               // scan chunk length
constexpr int NCHUNK = TT / LCH;       // 32

#define MFMA16(av, bv, cc) __builtin_amdgcn_mfma_f32_16x16x32_bf16((av), (bv), (cc), 0, 0, 0)

// native RNE conversion: compiles to v_cvt_pk_bf16_f32 (1 op / 1-2 values)
__device__ __forceinline__ u16 f2bf(float x) {
    union { __bf16 b; u16 u; } v; v.b = (__bf16)x; return v.u;
}
__device__ __forceinline__ u32 pk2bf(float lo, float hi) {
    union { bf16x2 v; u32 u; } c; c.v = bf16x2{(__bf16)lo, (__bf16)hi}; return c.u;
}
__device__ __forceinline__ float bf2f(u16 x) {
    union { u32 u; float f; } v; v.u = ((u32)x) << 16;
    return v.f;
}
__device__ __forceinline__ float gelu_tanh(float x) {
    // jax.nn.gelu default (approximate=True)
    float inner = 0.7978845608028654f * fmaf(0.044715f * x, x * x, x);
    float ez = __expf(2.f * inner);
    float t = 1.f - 2.f / (ez + 1.f);        // NaN-free tanh
    return 0.5f * x * (1.f + t);
}

// ---------------------------------------------------------------------------
__global__ void k0_prep(const float* __restrict__ Wpi, const float* __restrict__ bpi,
                        const float* __restrict__ fWin, const float* __restrict__ fbin,
                        const float* __restrict__ floga,
                        const float* __restrict__ bWin, const float* __restrict__ bbin,
                        const float* __restrict__ bloga,
                        const float* __restrict__ fW1, const float* __restrict__ bW1,
                        const float* __restrict__ fW2, const float* __restrict__ bW2,
                        const float* __restrict__ fb2, const float* __restrict__ bb2,
                        const float* __restrict__ fWout, const float* __restrict__ bWout,
                        const float* __restrict__ Wpo, const float* __restrict__ bpo,
                        u16* __restrict__ WuT, float* __restrict__ bu,
                        float* __restrict__ a_arr, float* __restrict__ l2a,
                        u16* __restrict__ W1Tbf, u16* __restrict__ W2poCatT,
                        u16* __restrict__ WoutTbf, u16* __restrict__ WpoCatT,
                        float* __restrict__ bc)
{
    const int blk = blockIdx.x, tid = threadIdx.x;
    if (blk < 64) {                       // WuT row n = (Wpi @ Win) column n
        const float* Win = (blk < 32) ? fWin : bWin;
        const int nn = blk & 31;
        float s = 0.f;
        #pragma unroll
        for (int d = 0; d < 32; ++d) s = fmaf(Wpi[tid * 32 + d], Win[d * 32 + nn], s);
        WuT[blk * 256 + tid] = f2bf(s);
        if (tid == 0) {
            const float* bin = (blk < 32) ? fbin : bbin;
            float sb = bin[nn];
            for (int d = 0; d < 32; ++d) sb = fmaf(bpi[d], Win[d * 32 + nn], sb);
            bu[blk] = sb;
        }
    } else if (blk == 64) {
        if (tid < 64) {                   // decay + log2
            const float* lg = (tid < 32) ? floga : bloga;
            float a = 1.f / (1.f + __expf(-lg[tid & 31]));
            a_arr[tid] = a;
            l2a[tid] = log2f(a);
        } else if (tid < 96) {            // bc = bpo + fb2@WpoF + bb2@WpoB
            int i = tid - 64;
            float s = bpo[i];
            for (int d = 0; d < 32; ++d) s = fmaf(fb2[d], Wpo[d * 32 + i], s);
            for (int d = 0; d < 32; ++d) s = fmaf(bb2[d], Wpo[(32 + d) * 32 + i], s);
            bc[i] = s;
        }
    } else if (blk == 65 || blk == 66) {  // W1T bf16 [dir][64n][32k]
        int dir = blk - 65;
        const float* W1 = dir ? bW1 : fW1;
        for (int x = tid; x < 2048; x += 256) {
            int n = x >> 5, k = x & 31;
            W1Tbf[dir * 2048 + n * 32 + k] = f2bf(W1[k * 64 + n]);
        }
    } else if (blk == 67 || blk == 68) {  // W2@Wpo fold -> [32n][128k], k=dir*64+j
        int dir = blk - 67;
        const float* W2 = dir ? bW2 : fW2;
        const float* Wp = Wpo + dir * 32 * 32;
        for (int x = tid; x < 2048; x += 256) {
            int j = x >> 5, i = x & 31;
            float s = 0.f;
            for (int d = 0; d < 32; ++d) s = fmaf(W2[j * 32 + d], Wp[d * 32 + i], s);
            W2poCatT[i * 128 + dir * 64 + j] = f2bf(s);
        }
    } else if (blk == 69 || blk == 70) {  // WoutT bf16 [dir][32n][32k]
        int dir = blk - 69;
        const float* Wout = dir ? bWout : fWout;
        for (int x = tid; x < 1024; x += 256) {
            int n = x >> 5, k = x & 31;
            WoutTbf[dir * 1024 + n * 32 + k] = f2bf(Wout[k * 32 + n]);
        }
    } else {                              // WpoCatT bf16 [32n][64k]
        for (int x = tid; x < 2048; x += 256) {
            int n = x >> 6, k = x & 63;
            WpoCatT[n * 64 + k] = f2bf(Wpo[k * 32 + n]);
        }
    }
}

// ---------------------------------------------------------------------------
// kA: fused projection + chunk-local scan. Block = (b, chunk) = 256 tokens.
// LDS: As 32x264 u16 (staging) + utile 256x64 u16 (u/h tile) + eSub. ~50 KB.
__global__ __launch_bounds__(256) void kA_proj_scan(const float* __restrict__ e,
    const u16* __restrict__ WuT, const float* __restrict__ bu,
    const float* __restrict__ a_arr, const float* __restrict__ l2a,
    u16* __restrict__ h, float* __restrict__ Ebuf)
{
    __shared__ __align__(16) u16 As[32][264];
    __shared__ __align__(16) u16 utile[256 * 64];
    __shared__ float eSub[64][4];
    const int tid = threadIdx.x;
    const int blk = blockIdx.x;
    const size_t t0 = (size_t)blk * 256;
    const int lane = tid & 63, wave = tid >> 6;
    const int row16 = lane & 15, quad = lane >> 4;
    const int wr = (wave & 1) * 16;          // sub-tile row offset for this wave
    const int wc = (wave >> 1) * 32;         // col offset

    #pragma unroll 1
    for (int s = 0; s < 8; ++s) {            // 8 sub-tiles of 32 tokens
        const float4* eg = reinterpret_cast<const float4*>(e + (t0 + s * 32) * 256);
        #pragma unroll
        for (int it = 0; it < 8; ++it) {
            int i = tid + it * 256;          // 2048 float4 = 32 rows x 256 k
            int r = i >> 6, kk = (i & 63) << 2;
            float4 v = eg[i];
            uint2 pk;
            pk.x = pk2bf(v.x, v.y);
            pk.y = pk2bf(v.z, v.w);
            *reinterpret_cast<uint2*>(&As[r][kk]) = pk;
        }
        __syncthreads();
        f32x4 acc[2] = {{0.f,0.f,0.f,0.f},{0.f,0.f,0.f,0.f}};
        #pragma unroll
        for (int ks = 0; ks < 8; ++ks) {
            bf16x8 av = *reinterpret_cast<const bf16x8*>(&As[wr + row16][ks * 32 + quad * 8]);
            #pragma unroll
            for (int c2 = 0; c2 < 2; ++c2) {
                bf16x8 bv = *reinterpret_cast<const bf16x8*>(WuT + (wc + c2 * 16 + row16) * 256 + ks * 32 + quad * 8);
                acc[c2] = MFMA16(av, bv, acc[c2]);
            }
        }
        #pragma unroll
        for (int c2 = 0; c2 < 2; ++c2) {     // C/D: col=lane&15, row=quad*4+r
            int col = wc + c2 * 16 + row16;
            float bias = bu[col];
            #pragma unroll
            for (int r = 0; r < 4; ++r) {
                int trow = s * 32 + wr + quad * 4 + r;
                utile[trow * 64 + col] = f2bf(acc[c2][r] + bias);
            }
        }
        __syncthreads();
    }

    // ---- chunk-local scan on utile (64 ch x 4 sub-chunks of 64) ----
    const int ch = tid & 63, sid = tid >> 6;
    const float a = a_arr[ch];
    const bool fwd = (ch < 32);
    float hh = 0.f;
    if (fwd) {
        for (int i = 0; i < 64; ++i) { int t = sid * 64 + i;
            hh = fmaf(a, hh, bf2f(utile[t * 64 + ch])); utile[t * 64 + ch] = f2bf(hh); }
    } else {
        for (int i = 63; i >= 0; --i) { int t = sid * 64 + i;
            hh = fmaf(a, hh, bf2f(utile[t * 64 + ch])); utile[t * 64 + ch] = f2bf(hh); }
    }
    eSub[ch][sid] = hh;
    __syncthreads();
    const float A = exp2f(64.f * l2a[ch]);               // a^64
    float cin = 0.f;
    if (fwd) { for (int j = 0; j < sid; ++j) cin = fmaf(A, cin, eSub[ch][j]); }
    else     { for (int j = 3; j > sid; --j) cin = fmaf(A, cin, eSub[ch][j]); }
    if (fwd && sid == 3)  Ebuf[(size_t)blk * 64 + ch] = fmaf(A, cin, eSub[ch][3]);
    if (!fwd && sid == 0) Ebuf[(size_t)blk * 64 + ch] = fmaf(A, cin, eSub[ch][0]);
    float p = cin;
    if (fwd) {
        for (int i = 0; i < 64; ++i) { int t = sid * 64 + i; p *= a;
            utile[t * 64 + ch] = f2bf(bf2f(utile[t * 64 + ch]) + p); }
    } else {
        for (int i = 63; i >= 0; --i) { int t = sid * 64 + i; p *= a;
            utile[t * 64 + ch] = f2bf(bf2f(utile[t * 64 + ch]) + p); }
    }
    __syncthreads();
    uint4* gw = reinterpret_cast<uint4*>(h + t0 * 64);
    const uint4* s4 = reinterpret_cast<const uint4*>(utile);
    #pragma unroll
    for (int i = 0; i < 8; ++i) gw[tid + 256 * i] = s4[tid + 256 * i];
}

// ---------------------------------------------------------------------------
// k3: cross-chunk carry scan. All 32 Ebuf values prefetched to registers
// (independent loads) before the serial chain -> one HBM latency, not 32.
__global__ void k3_carry(const float* __restrict__ Ebuf, float* __restrict__ Cin,
                         const float* __restrict__ l2a)
{
    int tid = blockIdx.x * 256 + threadIdx.x;
    if (tid >= BB * NCH) return;
    int b = tid >> 6, ch = tid & 63;
    float aL = exp2f((float)LCH * l2a[ch]);      // a^256
    const size_t base = (size_t)b * NCHUNK * 64 + ch;
    float ev[NCHUNK];
    #pragma unroll
    for (int c = 0; c < NCHUNK; ++c) ev[c] = Ebuf[base + (size_t)c * 64];
    float S = 0.f;
    if (ch < 32) {
        #pragma unroll
        for (int c = 0; c < NCHUNK; ++c) {
            Cin[base + (size_t)c * 64] = S; S = fmaf(aL, S, ev[c]);
        }
    } else {
        #pragma unroll
        for (int c = NCHUNK - 1; c >= 0; --c) {
            Cin[base + (size_t)c * 64] = S; S = fmaf(aL, S, ev[c]);
        }
    }
}

// ---------------------------------------------------------------------------
// kB: all-MFMA epilogue. Block = (b, chunk) = 256 tokens; wave owns 64 rows.
// No __syncthreads needed: every LDS region is produced & consumed by the
// same wave. XOR swizzle (colblock ^ row&7) kills the 16-way column-read
// conflicts on the 128B-stride tiles.
__global__ __launch_bounds__(256) void kB_out(const u16* __restrict__ h,
    const float* __restrict__ Cin, const float* __restrict__ l2a,
    const u16* __restrict__ WoutTbf, const float* __restrict__ fbout, const float* __restrict__ bbout,
    const u16* __restrict__ W1Tbf, const float* __restrict__ fb1, const float* __restrict__ bb1,
    const u16* __restrict__ WpoCatT, const u16* __restrict__ W2poCatT,
    const float* __restrict__ bc, float* __restrict__ out)
{
    __shared__ __align__(16) u16 Yt[256 * 64];       // [token][dir*32+n], swizzled
    __shared__ __align__(16) u16 Zw[4][16 * 128];    // per-wave scratch, swizzled
    const int tid = threadIdx.x;
    const int blk = blockIdx.x;
    const size_t t0 = (size_t)blk * 256;
    const int lane = tid & 63, wave = tid >> 6;
    const int row16 = lane & 15, quad = lane >> 4;
    const float* cinp = Cin + (size_t)blk * 64;      // uniform per block

    // ---- phase 1: Y = (h + cin*a^off) @ Wout + bout  -> Yt ----
    #pragma unroll 1
    for (int rr = 0; rr < 4; ++rr) {
        const int rt = wave * 4 + rr;
        const int kpos = rt * 16 + row16;            // token pos in chunk (A row m)
        #pragma unroll
        for (int dir = 0; dir < 2; ++dir) {
            uint4 hv = *reinterpret_cast<const uint4*>(h + (t0 + kpos) * 64 + dir * 32 + quad * 8);
            u32 hw[4] = {hv.x, hv.y, hv.z, hv.w};
            const float off = dir ? (float)(LCH - kpos) : (float)(kpos + 1);
            float ff[8];
            #pragma unroll
            for (int j = 0; j < 8; ++j) {
                int chn = dir * 32 + quad * 8 + j;
                float f = bf2f((u16)((hw[j >> 1] >> ((j & 1) * 16)) & 0xFFFFu));
                ff[j] = fmaf(cinp[chn], exp2f(off * l2a[chn]), f);
            }
            union { bf16x8 v; u32 w[4]; } af;
            #pragma unroll
            for (int jp = 0; jp < 4; ++jp) af.w[jp] = pk2bf(ff[2 * jp], ff[2 * jp + 1]);
            f32x4 yv[2] = {{0.f,0.f,0.f,0.f},{0.f,0.f,0.f,0.f}};
            #pragma unroll
            for (int nt = 0; nt < 2; ++nt) {
                bf16x8 bv = *reinterpret_cast<const bf16x8*>(WoutTbf + dir * 1024 + (nt * 16 + row16) * 32 + quad * 8);
                yv[nt] = MFMA16(af.v, bv, yv[nt]);
            }
            const float* boutp = dir ? bbout : fbout;
            #pragma unroll
            for (int nt = 0; nt < 2; ++nt) {
                float bb = boutp[nt * 16 + row16];
                #pragma unroll
                for (int r = 0; r < 4; ++r) {
                    int row = rt * 16 + quad * 4 + r;
                    int col = dir * 32 + nt * 16 + row16;
                    int cs = (col >> 3) ^ (row & 7);
                    Yt[row * 64 + cs * 8 + (col & 7)] = f2bf(yv[nt][r] + bb);
                }
            }
        }
    }

    // ---- phase 2: OUT = Ycat@Wpo + gelu(Y@W1+b1)@W2po + bc ----
    #pragma unroll 1
    for (int rr = 0; rr < 4; ++rr) {
        const int rt = wave * 4 + rr;
        const int arow = rt * 16 + row16;            // A row (token)
        f32x4 o0 = {0.f,0.f,0.f,0.f}, o1 = {0.f,0.f,0.f,0.f};

        // residual path: Ycat (K=64) @ WpoCat
        #pragma unroll
        for (int kb = 0; kb < 2; ++kb) {
            int cs = (kb * 4 + quad) ^ (arow & 7);
            bf16x8 av = *reinterpret_cast<const bf16x8*>(&Yt[arow * 64 + cs * 8]);
            bf16x8 bv0 = *reinterpret_cast<const bf16x8*>(WpoCatT + (row16) * 64 + kb * 32 + quad * 8);
            bf16x8 bv1 = *reinterpret_cast<const bf16x8*>(WpoCatT + (16 + row16) * 64 + kb * 32 + quad * 8);
            o0 = MFMA16(av, bv0, o0);
            o1 = MFMA16(av, bv1, o1);
        }
        // Z = gelu(Y_dir @ W1_dir + b1) -> Zw (per-wave, swizzled)
        #pragma unroll
        for (int dir = 0; dir < 2; ++dir) {
            int cs = (dir * 4 + quad) ^ (arow & 7);
            bf16x8 av = *reinterpret_cast<const bf16x8*>(&Yt[arow * 64 + cs * 8]);
            const float* b1p = dir ? bb1 : fb1;
            #pragma unroll
            for (int nt2 = 0; nt2 < 4; ++nt2) {
                f32x4 z = {0.f,0.f,0.f,0.f};
                bf16x8 bv = *reinterpret_cast<const bf16x8*>(W1Tbf + dir * 2048 + (nt2 * 16 + row16) * 32 + quad * 8);
                z = MFMA16(av, bv, z);
                float bb = b1p[nt2 * 16 + row16];
                #pragma unroll
                for (int r = 0; r < 4; ++r) {
                    float zz = gelu_tanh(z[r] + bb);
                    int zrow = quad * 4 + r;
                    int zcol = dir * 64 + nt2 * 16 + row16;
                    int zcs = (zcol >> 3) ^ (zrow & 7);
                    Zw[wave][zrow * 128 + zcs * 8 + (zcol & 7)] = f2bf(zz);
                }
            }
        }
        // MLP path: Zcat (K=128) @ W2poCat
        #pragma unroll
        for (int kb = 0; kb < 4; ++kb) {
            int zcs = (kb * 4 + quad) ^ (row16 & 7);
            bf16x8 av = *reinterpret_cast<const bf16x8*>(&Zw[wave][row16 * 128 + zcs * 8]);
            bf16x8 bv0 = *reinterpret_cast<const bf16x8*>(W2poCatT + (row16) * 128 + kb * 32 + quad * 8);
            bf16x8 bv1 = *reinterpret_cast<const bf16x8*>(W2poCatT + (16 + row16) * 128 + kb * 32 + quad * 8);
            o0 = MFMA16(av, bv0, o0);
            o1 = MFMA16(av, bv1, o1);
        }
        #pragma unroll
        for (int r = 0; r < 4; ++r) {
            size_t row = t0 + rt * 16 + quad * 4 + r;
            out[row * 32 + row16]      = o0[r] + bc[row16];
            out[row * 32 + 16 + row16] = o1[r] + bc[16 + row16];
        }
    }
}

// ---------------------------------------------------------------------------
extern "C" void kernel_launch(void* const* d_in, const int* in_sizes, int n_in,
                              void* d_out, int out_size, void* d_ws, size_t ws_size,
                              hipStream_t stream)
{
    (void)in_sizes; (void)n_in; (void)out_size; (void)ws_size;
    const float* e     = (const float*)d_in[0];
    const float* Wpi   = (const float*)d_in[1];
    const float* bpi   = (const float*)d_in[2];
    const float* Wpo   = (const float*)d_in[3];
    const float* bpo   = (const float*)d_in[4];
    const float* fWin  = (const float*)d_in[5];
    const float* fbin  = (const float*)d_in[6];
    const float* floga = (const float*)d_in[7];
    const float* fWout = (const float*)d_in[8];
    const float* fbout = (const float*)d_in[9];
    const float* fW1   = (const float*)d_in[10];
    const float* fb1   = (const float*)d_in[11];
    const float* fW2   = (const float*)d_in[12];
    const float* fb2   = (const float*)d_in[13];
    const float* bWin  = (const float*)d_in[14];
    const float* bbin  = (const float*)d_in[15];
    const float* bloga = (const float*)d_in[16];
    const float* bWout = (const float*)d_in[17];
    const float* bbout = (const float*)d_in[18];
    const float* bW1   = (const float*)d_in[19];
    const float* bb1   = (const float*)d_in[20];
    const float* bW2   = (const float*)d_in[21];
    const float* bb2   = (const float*)d_in[22];
    float* outp = (float*)d_out;

    char* ws = (char*)d_ws;
    size_t off = 0;
    auto walloc = [&](size_t bytes) { void* p = ws + off; off += (bytes + 255) & ~(size_t)255; return p; };
    u16*   hbuf  = (u16*)  walloc((size_t)BT * 64 * 2);       // 32 MB h_local
    u16*   WuT   = (u16*)  walloc(64 * 256 * 2);
    float* bu    = (float*)walloc(64 * 4);
    float* a_arr = (float*)walloc(64 * 4);
    float* l2a   = (float*)walloc(64 * 4);
    float* Ebuf  = (float*)walloc((size_t)BB * NCHUNK * 64 * 4);
    float* Cin   = (float*)walloc((size_t)BB * NCHUNK * 64 * 4);
    u16*   W1Tbf    = (u16*)walloc(2 * 64 * 32 * 2);
    u16*   W2poCatT = (u16*)walloc(32 * 128 * 2);
    u16*   WoutTbf  = (u16*)walloc(2 * 32 * 32 * 2);
    u16*   WpoCatT  = (u16*)walloc(32 * 64 * 2);
    float* bc    = (float*)walloc(32 * 4);

    k0_prep<<<72, 256, 0, stream>>>(Wpi, bpi, fWin, fbin, floga, bWin, bbin, bloga,
                                    fW1, bW1, fW2, bW2, fb2, bb2, fWout, bWout, Wpo, bpo,
                                    WuT, bu, a_arr, l2a, W1Tbf, W2poCatT, WoutTbf, WpoCatT, bc);
    kA_proj_scan<<<BB * NCHUNK, 256, 0, stream>>>(e, WuT, bu, a_arr, l2a, hbuf, Ebuf);
    k3_carry<<<8, 256, 0, stream>>>(Ebuf, Cin, l2a);
    kB_out<<<BB * NCHUNK, 256, 0, stream>>>(hbuf, Cin, l2a,
                                            WoutTbf, fbout, bbout,
                                            W1Tbf, fb1, bb1,
                                            WpoCatT, W2poCatT, bc, outp);
}